// Round 12
// baseline (28.515 us; speedup 1.0000x reference)
//
#include <hip/hip_runtime.h>
#include <hip/hip_fp16.h>
#include <math.h>

#define N_G    512
#define IMG_H  256
#define IMG_W  256

// Kernel A: 8 blocks x 64 threads. Each block cooperatively builds the full
// tz table in LDS (64 thr x 8 entries); each thread preprocesses one gaussian
// in registers, ranks its tz against the table (float4 LDS broadcasts), and
// scatters packed planes to the GLOBALLY DEPTH-SORTED slot:
//   Gs[r] = {px, py, cull_rad, tz}                  (scan plane; rad<0 = culled)
//   Ga[r] = {-A/(2ln2), -B/ln2, -C/(2ln2), log2op}  (blend plane, exp2-ready)
//   Gb[r] = {half2(col_r,col_g), col_b}             (color plane)
// radii_out stays in ORIGINAL order.
__global__ __launch_bounds__(64) void gs_prep(
    const float* __restrict__ means3D,
    const float* __restrict__ opacities,
    const float* __restrict__ colors,
    const float* __restrict__ scales,
    const float* __restrict__ rotations,
    const float* __restrict__ viewmatrix,
    const float* __restrict__ projmatrix,
    float4* __restrict__ Gs,
    float4* __restrict__ Ga,
    float2* __restrict__ Gb,
    float* __restrict__ radii_out)
{
    __shared__ float s_tz[N_G];
    const int tid = threadIdx.x;
    const int g = blockIdx.x * 64 + tid;

    float VM[16], PM[16];
    #pragma unroll
    for (int i = 0; i < 16; ++i) { VM[i] = viewmatrix[i]; PM[i] = projmatrix[i]; }

    // cooperative tz table (same formula as below -> bitwise-identical keys)
    #pragma unroll
    for (int q = 0; q < 8; ++q) {
        const int j = tid * 8 + q;
        s_tz[j] = VM[8]*means3D[j*3+0] + VM[9]*means3D[j*3+1]
                + VM[10]*means3D[j*3+2] + VM[11];
    }

    const float mx = means3D[g*3+0], my = means3D[g*3+1], mz = means3D[g*3+2];
    float rq = rotations[g*4+0], xq = rotations[g*4+1], yq = rotations[g*4+2], zq = rotations[g*4+3];
    const float qn = sqrtf(rq*rq + xq*xq + yq*yq + zq*zq);
    rq /= qn; xq /= qn; yq /= qn; zq /= qn;
    const float R00 = 1.f - 2.f*(yq*yq + zq*zq);
    const float R01 = 2.f*(xq*yq - rq*zq);
    const float R02 = 2.f*(xq*zq + rq*yq);
    const float R10 = 2.f*(xq*yq + rq*zq);
    const float R11 = 1.f - 2.f*(xq*xq + zq*zq);
    const float R12 = 2.f*(yq*zq - rq*xq);
    const float R20 = 2.f*(xq*zq - rq*yq);
    const float R21 = 2.f*(yq*zq + rq*xq);
    const float R22 = 1.f - 2.f*(xq*xq + yq*yq);
    float s0 = scales[g*3+0], s1 = scales[g*3+1], s2 = scales[g*3+2];
    s0 *= s0; s1 *= s1; s2 *= s2;
    const float S00 = R00*R00*s0 + R01*R01*s1 + R02*R02*s2;
    const float S01 = R00*R10*s0 + R01*R11*s1 + R02*R12*s2;
    const float S02 = R00*R20*s0 + R01*R21*s1 + R02*R22*s2;
    const float S11 = R10*R10*s0 + R11*R11*s1 + R12*R12*s2;
    const float S12 = R10*R20*s0 + R11*R21*s1 + R12*R22*s2;
    const float S22 = R20*R20*s0 + R21*R21*s1 + R22*R22*s2;

    const float pv0 = VM[0]*mx + VM[1]*my + VM[2]*mz  + VM[3];
    const float pv1 = VM[4]*mx + VM[5]*my + VM[6]*mz  + VM[7];
    const float tz  = VM[8]*mx + VM[9]*my + VM[10]*mz + VM[11];
    const float FX = 256.f, FY = 256.f, limx = 0.65f, limy = 0.65f;
    const float tx = fminf(fmaxf(pv0/tz, -limx), limx) * tz;
    const float ty = fminf(fmaxf(pv1/tz, -limy), limy) * tz;
    const float itz = 1.f / tz, itz2 = itz*itz;
    const float J00 = FX*itz, J02 = -FX*tx*itz2;
    const float J11 = FY*itz, J12 = -FY*ty*itz2;
    const float T00 = J00*VM[0] + J02*VM[8];
    const float T01 = J00*VM[1] + J02*VM[9];
    const float T02 = J00*VM[2] + J02*VM[10];
    const float T10 = J11*VM[4] + J12*VM[8];
    const float T11 = J11*VM[5] + J12*VM[9];
    const float T12 = J11*VM[6] + J12*VM[10];
    const float u0 = T00*S00 + T01*S01 + T02*S02;
    const float u1 = T00*S01 + T01*S11 + T02*S12;
    const float u2 = T00*S02 + T01*S12 + T02*S22;
    const float v0 = T10*S00 + T11*S01 + T12*S02;
    const float v1 = T10*S01 + T11*S11 + T12*S12;
    const float v2 = T10*S02 + T11*S12 + T12*S22;
    const float c00 = u0*T00 + u1*T01 + u2*T02;
    const float c01 = u0*T10 + u1*T11 + u2*T12;
    const float c11 = v0*T10 + v1*T11 + v2*T12;
    const float a = c00 + 0.3f, b = c01, c = c11 + 0.3f;
    const float det = a*c - b*b;
    const float inv_det = 1.f/det;
    float conA = c*inv_det, conB = -b*inv_det, conC = a*inv_det;
    const float ph0 = PM[0]*mx  + PM[1]*my  + PM[2]*mz  + PM[3];
    const float ph1 = PM[4]*mx  + PM[5]*my  + PM[6]*mz  + PM[7];
    const float ph3 = PM[12]*mx + PM[13]*my + PM[14]*mz + PM[15];
    const float pw = 1.f/(ph3 + 1e-7f);
    const float pix_x = ((ph0*pw + 1.f)*(float)IMG_W - 1.f)*0.5f;
    const float pix_y = ((ph1*pw + 1.f)*(float)IMG_H - 1.f)*0.5f;
    const float mid = 0.5f*(a + c);
    const float lam = mid + sqrtf(fmaxf(0.1f, mid*mid - det));
    const bool valid = (tz > 0.2f) && (det > 0.f);
    float op = opacities[g];
    if (!valid) { conA = conB = conC = 0.f; op = 0.f; }

    radii_out[g] = valid ? ceilf(3.f*sqrtf(lam)) : 0.f;

    // Conservative cull radius: al >= 1/255 needs |d|^2 <= 2*lam*ln(255*op)
    // (lam >= lambda_max of regularized cov2d: sqrt arg is clamped upward).
    float rad = -1.f;
    if (valid && op * 255.f > 1.f) {
        const float r = sqrtf(2.f * lam * logf(255.f * op)) + 0.01f;
        if (pix_x + r >= 0.f && pix_x - r <= (float)(IMG_W-1) &&
            pix_y + r >= 0.f && pix_y - r <= (float)(IMG_H-1))
            rad = r;
    }

    __syncthreads();   // tz table complete

    // stable global counting-rank on (tz, idx), float4-vectorized LDS broadcasts
    int rk = 0;
    const float4* t4 = (const float4*)s_tz;
    #pragma unroll 8
    for (int j4 = 0; j4 < N_G/4; ++j4) {
        const float4 t = t4[j4];
        const int j = j4 * 4;
        rk += (t.x < tz) || (t.x == tz && (j+0) < g);
        rk += (t.y < tz) || (t.y == tz && (j+1) < g);
        rk += (t.z < tz) || (t.z == tz && (j+2) < g);
        rk += (t.w < tz) || (t.w == tz && (j+3) < g);
    }

    const float il2 = 1.4426950408889634f;  // 1/ln2
    const float l2op = log2f(op);           // op==0 -> -inf -> al 0 (rad<0 anyway)
    const float rg = __builtin_bit_cast(float, __floats2half2_rn(colors[g*3+0], colors[g*3+1]));
    Gs[rk] = make_float4(pix_x, pix_y, rad, tz);
    Ga[rk] = make_float4(-0.5f*conA*il2, -conB*il2, -0.5f*conC*il2, l2op);
    Gb[rk] = make_float2(rg, colors[g*3+2]);
}

// Kernel B: 512 blocks x 128 threads, one 16x8 tile per block. Input is
// depth-sorted, so compaction is IN-ORDER: wave w owns contiguous ranks
// [w*256,(w+1)*256) as 4 lane-ordered chunks; 4 ballots + mbcnt give each
// hit its ordered slot; one cross-wave base exchange. No rank loop. Blend
// planes gathered conditionally at append (single L2 epoch).
__global__ __launch_bounds__(128) void gs_raster(
    const float4* __restrict__ Gs,
    const float4* __restrict__ Ga,
    const float2* __restrict__ Gb,
    const float* __restrict__ bg,
    float* __restrict__ img)
{
    __shared__ int    s_wn[2];
    __shared__ float2 oP[N_G + 8];   // {px,py}          depth-ordered compact
    __shared__ float4 oA[N_G + 8];   // {qa,qb,qc,l2op}
    __shared__ float2 oC[N_G + 8];   // {rg_half2, cb}

    const int tid  = threadIdx.x;
    const int w    = tid >> 6;         // wave id (0/1)
    const int lane = tid & 63;
    const int bx = blockIdx.x & 15, by = blockIdx.x >> 4;   // 16x32 grid of 16x8
    const float x0 = (float)(bx * 16), x1 = x0 + 15.f;
    const float y0 = (float)(by * 8),  y1 = y0 + 7.f;

    // load own contiguous 256-range (4 chunks of 64, lane-ordered)
    float4 s[4];
    #pragma unroll
    for (int c = 0; c < 4; ++c) s[c] = Gs[w*256 + c*64 + lane];

    // hit tests + per-chunk ballots (in rank order)
    bool hit[4];
    unsigned long long msk[4];
    int wave_cnt = 0;
    #pragma unroll
    for (int c = 0; c < 4; ++c) {
        hit[c] = (s[c].z > 0.f &&
                  s[c].x + s[c].z >= x0 && s[c].x - s[c].z <= x1 &&
                  s[c].y + s[c].z >= y0 && s[c].y - s[c].z <= y1);
        msk[c] = __ballot(hit[c]);
        wave_cnt += __popcll(msk[c]);
    }
    if (lane == 0) s_wn[w] = wave_cnt;
    __syncthreads();

    const int w0 = s_wn[0];
    const int nc = w0 + s_wn[1];
    const int ncp = (nc + 7) & ~7;
    int pos = (w == 0) ? 0 : w0;

    // in-order append; conditional gather of blend planes from L2
    #pragma unroll
    for (int c = 0; c < 4; ++c) {
        if (hit[c]) {
            const int g = w*256 + c*64 + lane;
            const int p = pos + __builtin_amdgcn_mbcnt_hi(
                (unsigned)(msk[c] >> 32),
                __builtin_amdgcn_mbcnt_lo((unsigned)msk[c], 0));
            oP[p] = make_float2(s[c].x, s[c].y);
            oA[p] = Ga[g];
            oC[p] = Gb[g];
        }
        pos += __popcll(msk[c]);
    }
    for (int i = nc + tid; i < ncp; i += 128) {   // pad: l2op=-1e30 -> skipped
        oP[i] = make_float2(0.f, 0.f);
        oA[i] = make_float4(0.f, 0.f, 0.f, -1e30f);
        oC[i] = make_float2(0.f, 0.f);
    }
    __syncthreads();

    // front-to-back blend, one pixel per thread
    const int px = bx * 16 + (tid & 15), py = by * 8 + (tid >> 4);
    const float fx = (float)px, fy = (float)py;

    float T = 1.f, cr = 0.f, cg = 0.f, cb = 0.f;
    bool done = false;
    for (int base = 0; base < ncp; base += 8) {
        #pragma unroll
        for (int u = 0; u < 8; ++u) {
            const int i = base + u;
            const float2 pP = oP[i];
            const float4 pA = oA[i];
            const float2 pC = oC[i];
            const float dx = pP.x - fx;
            const float dy = pP.y - fy;
            const float power = pA.x*dx*dx + pA.y*dx*dy + pA.z*dy*dy;  // log2-scaled
            const float al = fminf(0.99f, __builtin_amdgcn_exp2f(power + pA.w));
            if (!done && !(power > 0.f || al < (1.0f/255.0f))) {
                const float Tnew = T * (1.f - al);
                if (Tnew < 1e-4f) { T = Tnew; done = true; }
                else {
                    const float wgt = al * T;
                    const float2 rg = __half22float2(__builtin_bit_cast(__half2, pC.x));
                    cr += wgt * rg.x;
                    cg += wgt * rg.y;
                    cb += wgt * pC.y;
                    T = Tnew;
                }
            }
        }
        if (__all(done)) break;
    }
    const int pix = py * IMG_W + px;
    img[pix]                   = cr + T * bg[0];
    img[IMG_H*IMG_W   + pix]   = cg + T * bg[1];
    img[2*IMG_H*IMG_W + pix]   = cb + T * bg[2];
}

extern "C" void kernel_launch(void* const* d_in, const int* in_sizes, int n_in,
                              void* d_out, int out_size, void* d_ws, size_t ws_size,
                              hipStream_t stream) {
    const float* means3D    = (const float*)d_in[0];
    // d_in[1] = means2D (unused by reference math)
    const float* opacities  = (const float*)d_in[2];
    const float* colors     = (const float*)d_in[3];
    const float* scales     = (const float*)d_in[4];
    const float* rotations  = (const float*)d_in[5];
    const float* viewmatrix = (const float*)d_in[6];
    const float* projmatrix = (const float*)d_in[7];
    const float* bg         = (const float*)d_in[8];

    float* img   = (float*)d_out;                   // 3*256*256
    float* radii = (float*)d_out + 3*IMG_H*IMG_W;   // 512 (as float values)
    float4* Gs   = (float4*)d_ws;                   // 512 float4
    float4* Ga   = Gs + N_G;                        // 512 float4
    float2* Gb   = (float2*)(Ga + N_G);             // 512 float2

    gs_prep<<<8, 64, 0, stream>>>(means3D, opacities, colors, scales,
                                  rotations, viewmatrix, projmatrix,
                                  Gs, Ga, Gb, radii);
    gs_raster<<<(IMG_W/16)*(IMG_H/8), 128, 0, stream>>>(Gs, Ga, Gb, bg, img);
}

// Round 13
// 18.169 us; speedup vs baseline: 1.5694x; 1.5694x over previous
//
#include <hip/hip_runtime.h>
#include <hip/hip_fp16.h>
#include <math.h>

#define N_G    512
#define IMG_H  256
#define IMG_W  256

// Kernel A (champion R5 prep + exp2 packing): 8 blocks x 64 threads, one
// gaussian per thread, registers only, ORIGINAL-ORDER planes:
//   Gs[g] = {px, py, cull_rad, tz}                  (scan plane; rad<0 = culled)
//   Ga[g] = {-A/(2ln2), -B/ln2, -C/(2ln2), log2op}  (blend plane, exp2-ready)
//   Gb[g] = {half2(col_r,col_g), col_b}             (color plane)
__global__ __launch_bounds__(64) void gs_prep(
    const float* __restrict__ means3D,
    const float* __restrict__ opacities,
    const float* __restrict__ colors,
    const float* __restrict__ scales,
    const float* __restrict__ rotations,
    const float* __restrict__ viewmatrix,
    const float* __restrict__ projmatrix,
    float4* __restrict__ Gs,
    float4* __restrict__ Ga,
    float2* __restrict__ Gb,
    float* __restrict__ radii_out)
{
    const int g = blockIdx.x * 64 + threadIdx.x;

    float VM[16], PM[16];
    #pragma unroll
    for (int i = 0; i < 16; ++i) { VM[i] = viewmatrix[i]; PM[i] = projmatrix[i]; }

    const float mx = means3D[g*3+0], my = means3D[g*3+1], mz = means3D[g*3+2];
    float rq = rotations[g*4+0], xq = rotations[g*4+1], yq = rotations[g*4+2], zq = rotations[g*4+3];
    const float qn = sqrtf(rq*rq + xq*xq + yq*yq + zq*zq);
    rq /= qn; xq /= qn; yq /= qn; zq /= qn;
    const float R00 = 1.f - 2.f*(yq*yq + zq*zq);
    const float R01 = 2.f*(xq*yq - rq*zq);
    const float R02 = 2.f*(xq*zq + rq*yq);
    const float R10 = 2.f*(xq*yq + rq*zq);
    const float R11 = 1.f - 2.f*(xq*xq + zq*zq);
    const float R12 = 2.f*(yq*zq - rq*xq);
    const float R20 = 2.f*(xq*zq - rq*yq);
    const float R21 = 2.f*(yq*zq + rq*xq);
    const float R22 = 1.f - 2.f*(xq*xq + yq*yq);
    float s0 = scales[g*3+0], s1 = scales[g*3+1], s2 = scales[g*3+2];
    s0 *= s0; s1 *= s1; s2 *= s2;
    const float S00 = R00*R00*s0 + R01*R01*s1 + R02*R02*s2;
    const float S01 = R00*R10*s0 + R01*R11*s1 + R02*R12*s2;
    const float S02 = R00*R20*s0 + R01*R21*s1 + R02*R22*s2;
    const float S11 = R10*R10*s0 + R11*R11*s1 + R12*R12*s2;
    const float S12 = R10*R20*s0 + R11*R21*s1 + R12*R22*s2;
    const float S22 = R20*R20*s0 + R21*R21*s1 + R22*R22*s2;

    const float pv0 = VM[0]*mx + VM[1]*my + VM[2]*mz  + VM[3];
    const float pv1 = VM[4]*mx + VM[5]*my + VM[6]*mz  + VM[7];
    const float tz  = VM[8]*mx + VM[9]*my + VM[10]*mz + VM[11];
    const float FX = 256.f, FY = 256.f, limx = 0.65f, limy = 0.65f;
    const float tx = fminf(fmaxf(pv0/tz, -limx), limx) * tz;
    const float ty = fminf(fmaxf(pv1/tz, -limy), limy) * tz;
    const float itz = 1.f / tz, itz2 = itz*itz;
    const float J00 = FX*itz, J02 = -FX*tx*itz2;
    const float J11 = FY*itz, J12 = -FY*ty*itz2;
    const float T00 = J00*VM[0] + J02*VM[8];
    const float T01 = J00*VM[1] + J02*VM[9];
    const float T02 = J00*VM[2] + J02*VM[10];
    const float T10 = J11*VM[4] + J12*VM[8];
    const float T11 = J11*VM[5] + J12*VM[9];
    const float T12 = J11*VM[6] + J12*VM[10];
    const float u0 = T00*S00 + T01*S01 + T02*S02;
    const float u1 = T00*S01 + T01*S11 + T02*S12;
    const float u2 = T00*S02 + T01*S12 + T02*S22;
    const float v0 = T10*S00 + T11*S01 + T12*S02;
    const float v1 = T10*S01 + T11*S11 + T12*S12;
    const float v2 = T10*S02 + T11*S12 + T12*S22;
    const float c00 = u0*T00 + u1*T01 + u2*T02;
    const float c01 = u0*T10 + u1*T11 + u2*T12;
    const float c11 = v0*T10 + v1*T11 + v2*T12;
    const float a = c00 + 0.3f, b = c01, c = c11 + 0.3f;
    const float det = a*c - b*b;
    const float inv_det = 1.f/det;
    float conA = c*inv_det, conB = -b*inv_det, conC = a*inv_det;
    const float ph0 = PM[0]*mx  + PM[1]*my  + PM[2]*mz  + PM[3];
    const float ph1 = PM[4]*mx  + PM[5]*my  + PM[6]*mz  + PM[7];
    const float ph3 = PM[12]*mx + PM[13]*my + PM[14]*mz + PM[15];
    const float pw = 1.f/(ph3 + 1e-7f);
    const float pix_x = ((ph0*pw + 1.f)*(float)IMG_W - 1.f)*0.5f;
    const float pix_y = ((ph1*pw + 1.f)*(float)IMG_H - 1.f)*0.5f;
    const float mid = 0.5f*(a + c);
    const float lam = mid + sqrtf(fmaxf(0.1f, mid*mid - det));
    const bool valid = (tz > 0.2f) && (det > 0.f);
    float op = opacities[g];
    if (!valid) { conA = conB = conC = 0.f; op = 0.f; }

    radii_out[g] = valid ? ceilf(3.f*sqrtf(lam)) : 0.f;

    // Conservative cull radius: al >= 1/255 needs |d|^2 <= 2*lam*ln(255*op)
    // (lam >= lambda_max of regularized cov2d: sqrt arg is clamped upward).
    float rad = -1.f;
    if (valid && op * 255.f > 1.f) {
        const float r = sqrtf(2.f * lam * logf(255.f * op)) + 0.01f;
        if (pix_x + r >= 0.f && pix_x - r <= (float)(IMG_W-1) &&
            pix_y + r >= 0.f && pix_y - r <= (float)(IMG_H-1))
            rad = r;
    }

    const float il2 = 1.4426950408889634f;  // 1/ln2
    const float l2op = log2f(op);           // op==0 -> -inf -> al 0 (rad<0 anyway)
    const float rg = __builtin_bit_cast(float, __floats2half2_rn(colors[g*3+0], colors[g*3+1]));
    Gs[g] = make_float4(pix_x, pix_y, rad, tz);
    Ga[g] = make_float4(-0.5f*conA*il2, -conB*il2, -0.5f*conC*il2, l2op);
    Gb[g] = make_float2(rg, colors[g*3+2]);
}

// Kernel B (champion raster, bigger tiles): 256 blocks x 256 threads, one
// 16x16 tile per block. Coalesced scan (2 float4 per thread) -> LDS key
// append -> per-tile stable rank by (tz, id) over the nc-entry subset
// (== stable global argsort restricted to the covering set) -> gather
// planes by id (L2-hot) into ordered slots -> blend with exp2.
__global__ __launch_bounds__(256) void gs_raster(
    const float4* __restrict__ Gs,
    const float4* __restrict__ Ga,
    const float2* __restrict__ Gb,
    const float* __restrict__ bg,
    float* __restrict__ img)
{
    __shared__ int    s_n;
    __shared__ float2 s_key[N_G];   // {tz, bits(id)} of covering gaussians
    __shared__ float2 oP[N_G];      // {px,py}           depth-ordered
    __shared__ float4 oA[N_G];      // {qa,qb,qc,l2op}
    __shared__ float2 oC[N_G];      // {rg_half2, cb}

    const int tid = threadIdx.x;
    const int bx = blockIdx.x & 15, by = blockIdx.x >> 4;   // 16x16 grid of 16x16 tiles
    const float x0 = (float)(bx * 16), x1 = x0 + 15.f;
    const float y0 = (float)(by * 16), y1 = y0 + 15.f;

    if (tid == 0) s_n = 0;

    // coalesced scan: 2 gaussians per thread, one load burst
    float4 s[2];
    #pragma unroll
    for (int k = 0; k < 2; ++k) s[k] = Gs[k * 256 + tid];
    __syncthreads();   // covers s_n init

    // hit test + key append
    #pragma unroll
    for (int k = 0; k < 2; ++k) {
        const bool hit = (s[k].z > 0.f &&
                          s[k].x + s[k].z >= x0 && s[k].x - s[k].z <= x1 &&
                          s[k].y + s[k].z >= y0 && s[k].y - s[k].z <= y1);
        if (hit) {
            const int p = atomicAdd(&s_n, 1);
            s_key[p] = make_float2(s[k].w, __int_as_float(k * 256 + tid));
        }
    }
    __syncthreads();

    const int nc  = s_n;
    const int ncp = (nc + 7) & ~7;

    // stable rank by (tz, original id) + gather planes by id (L2-hot)
    for (int i = tid; i < nc; i += 256) {
        const float2 ki = s_key[i];
        const float tz = ki.x;
        const int   id = __float_as_int(ki.y);
        int r = 0;
        for (int j = 0; j < nc; ++j) {
            const float2 kj = s_key[j];
            r += (kj.x < tz) || (kj.x == tz && __float_as_int(kj.y) < id);
        }
        const float4 w0 = Gs[id];
        oP[r] = make_float2(w0.x, w0.y);
        oA[r] = Ga[id];
        oC[r] = Gb[id];
    }
    for (int i = nc + tid; i < ncp; i += 256) {   // pad: l2op=-1e30 -> skipped
        oP[i] = make_float2(0.f, 0.f);
        oA[i] = make_float4(0.f, 0.f, 0.f, -1e30f);
        oC[i] = make_float2(0.f, 0.f);
    }
    __syncthreads();

    // front-to-back blend, one pixel per thread
    const int px = bx * 16 + (tid & 15), py = by * 16 + (tid >> 4);
    const float fx = (float)px, fy = (float)py;

    float T = 1.f, cr = 0.f, cg = 0.f, cb = 0.f;
    bool done = false;
    for (int base = 0; base < ncp; base += 8) {
        #pragma unroll
        for (int u = 0; u < 8; ++u) {
            const int i = base + u;
            const float2 pP = oP[i];
            const float4 pA = oA[i];
            const float2 pC = oC[i];
            const float dx = pP.x - fx;
            const float dy = pP.y - fy;
            const float power = pA.x*dx*dx + pA.y*dx*dy + pA.z*dy*dy;  // log2-scaled
            const float al = fminf(0.99f, __builtin_amdgcn_exp2f(power + pA.w));
            if (!done && !(power > 0.f || al < (1.0f/255.0f))) {
                const float Tnew = T * (1.f - al);
                if (Tnew < 1e-4f) { T = Tnew; done = true; }
                else {
                    const float wgt = al * T;
                    const float2 rg = __half22float2(__builtin_bit_cast(__half2, pC.x));
                    cr += wgt * rg.x;
                    cg += wgt * rg.y;
                    cb += wgt * pC.y;
                    T = Tnew;
                }
            }
        }
        if (__all(done)) break;
    }
    const int pix = py * IMG_W + px;
    img[pix]                   = cr + T * bg[0];
    img[IMG_H*IMG_W   + pix]   = cg + T * bg[1];
    img[2*IMG_H*IMG_W + pix]   = cb + T * bg[2];
}

extern "C" void kernel_launch(void* const* d_in, const int* in_sizes, int n_in,
                              void* d_out, int out_size, void* d_ws, size_t ws_size,
                              hipStream_t stream) {
    const float* means3D    = (const float*)d_in[0];
    // d_in[1] = means2D (unused by reference math)
    const float* opacities  = (const float*)d_in[2];
    const float* colors     = (const float*)d_in[3];
    const float* scales     = (const float*)d_in[4];
    const float* rotations  = (const float*)d_in[5];
    const float* viewmatrix = (const float*)d_in[6];
    const float* projmatrix = (const float*)d_in[7];
    const float* bg         = (const float*)d_in[8];

    float* img   = (float*)d_out;                   // 3*256*256
    float* radii = (float*)d_out + 3*IMG_H*IMG_W;   // 512 (as float values)
    float4* Gs   = (float4*)d_ws;                   // 512 float4
    float4* Ga   = Gs + N_G;                        // 512 float4
    float2* Gb   = (float2*)(Ga + N_G);             // 512 float2

    gs_prep<<<8, 64, 0, stream>>>(means3D, opacities, colors, scales,
                                  rotations, viewmatrix, projmatrix,
                                  Gs, Ga, Gb, radii);
    gs_raster<<<(IMG_W/16)*(IMG_H/16), 256, 0, stream>>>(Gs, Ga, Gb, bg, img);
}